// Round 6
// baseline (543.998 us; speedup 1.0000x reference)
//
#include <hip/hip_runtime.h>
#include <stdint.h>
#include <math.h>

typedef unsigned int uint_t;

#define FEAT 2048
#define DSTRIDE 2052   // FEAT + HIDDEN
#define WARM 96
#define STEPS (WARM + 32)
#define NN 8192

__device__ __forceinline__ float sigm(float x) { return 1.f / (1.f + expf(-x)); }

// ---------------------------------------------------------------------------
// K1 (f32 inputs): px2[(n%32)][(n/32)][gq] = feat[n,:]·Wx[gq,:2048] + b + th
// 512 blocks x 16 rows; W (16x2048 f32 = 128 KB) staged via LDS in four
// 32 KB chunks. px2 = 512 KB at the head of d_out (f32 rows 0..63), consumed
// by k_scan before k_out_main overwrites it.
// ---------------------------------------------------------------------------
__global__ __launch_bounds__(256) void k_px(
    const float* __restrict__ feat,
    const float* __restrict__ Wf, const float* __restrict__ Wi,
    const float* __restrict__ Wg, const float* __restrict__ Wo,
    const float* __restrict__ bfp, const float* __restrict__ bip,
    const float* __restrict__ bgp, const float* __restrict__ bop,
    const float* __restrict__ thf, const float* __restrict__ thi,
    const float* __restrict__ thg, const float* __restrict__ tho,
    float* __restrict__ px2)
{
    __shared__ float Wl[16 * 512];
    const int t = threadIdx.x;
    const int wave = t >> 6, lane = t & 63;
    const int rowBase = blockIdx.x * 16;
    const float* Ws[4] = {Wf, Wi, Wg, Wo};

    float acc[4][16];
#pragma unroll
    for (int r = 0; r < 4; ++r)
#pragma unroll
        for (int i = 0; i < 16; ++i) acc[r][i] = 0.f;

    for (int ch = 0; ch < 4; ++ch) {
        __syncthreads();
        for (int i4 = t; i4 < 2048; i4 += 256) {
            const int gq = i4 >> 7;
            const int jj = (i4 & 127) << 2;
            const int g = gq >> 2, q = gq & 3;
            const float4 v = *(const float4*)(Ws[g] + q * DSTRIDE + ch * 512 + jj);
            *(float4*)(&Wl[gq * 512 + jj]) = v;
        }
        __syncthreads();
#pragma unroll
        for (int rr = 0; rr < 4; ++rr) {
            const int n = rowBase + wave * 4 + rr;
            const float* fp = feat + (size_t)n * FEAT + ch * 512 + lane * 8;
            const float4 fa = *(const float4*)(fp);
            const float4 fb = *(const float4*)(fp + 4);
#pragma unroll
            for (int gq = 0; gq < 16; ++gq) {
                const float4 wa = *(const float4*)(&Wl[gq * 512 + lane * 8]);
                const float4 wb = *(const float4*)(&Wl[gq * 512 + lane * 8 + 4]);
                float a = acc[rr][gq];
                a = fmaf(fa.x, wa.x, a); a = fmaf(fa.y, wa.y, a);
                a = fmaf(fa.z, wa.z, a); a = fmaf(fa.w, wa.w, a);
                a = fmaf(fb.x, wb.x, a); a = fmaf(fb.y, wb.y, a);
                a = fmaf(fb.z, wb.z, a); a = fmaf(fb.w, wb.w, a);
                acc[rr][gq] = a;
            }
        }
    }

    float bth[16];
    {
        const float* bs[4] = {bfp, bip, bgp, bop};
        const float* ts[4] = {thf, thi, thg, tho};
#pragma unroll
        for (int g = 0; g < 4; ++g)
#pragma unroll
            for (int q = 0; q < 4; ++q)
                bth[g * 4 + q] = bs[g][q] + ts[g][q];
    }

#pragma unroll
    for (int rr = 0; rr < 4; ++rr) {
#pragma unroll
        for (int i = 0; i < 16; ++i) {
            float v = acc[rr][i];
#pragma unroll
            for (int m = 32; m > 0; m >>= 1) v += __shfl_xor(v, m, 64);
            acc[rr][i] = v + bth[i];
        }
        if (lane == 0) {
            const int n = rowBase + wave * 4 + rr;
            float* dst = px2 + ((size_t)(n & 31) * 256 + (n >> 5)) * 16;
            *(float4*)(dst + 0)  = make_float4(acc[rr][0],  acc[rr][1],  acc[rr][2],  acc[rr][3]);
            *(float4*)(dst + 4)  = make_float4(acc[rr][4],  acc[rr][5],  acc[rr][6],  acc[rr][7]);
            *(float4*)(dst + 8)  = make_float4(acc[rr][8],  acc[rr][9],  acc[rr][10], acc[rr][11]);
            *(float4*)(dst + 12) = make_float4(acc[rr][12], acc[rr][13], acc[rr][14], acc[rr][15]);
        }
    }
}

// ---------------------------------------------------------------------------
// K2: chunked scan — PROVEN bit-equivalent to the exact serial scan (R5).
// 256 chunks x 32 steps, 96-step warmup from (h,c)=(0,0). One 256-thread
// block. hout = LAST 128 KB of d_out (f32 rows 8176..8191).
// qlayer(z,th) = [c1c2c3, c0c1, c0c1c2, c0c1c2c3], c_w = cos(z_w + th_w)
// (theta pre-added by k_px). Libm (fast-math variant is the next round).
// ---------------------------------------------------------------------------
__global__ __launch_bounds__(256) void k_scan(
    const float* __restrict__ Wf, const float* __restrict__ Wi,
    const float* __restrict__ Wg, const float* __restrict__ Wo,
    const float* __restrict__ px2, float* __restrict__ hout)
{
    const int c = threadIdx.x;   // chunk id 0..255
    float wh[4][4][4];           // [gate][q][j]
    {
        const float* Ws[4] = {Wf, Wi, Wg, Wo};
#pragma unroll
        for (int g = 0; g < 4; ++g)
#pragma unroll
            for (int q = 0; q < 4; ++q)
#pragma unroll
                for (int j = 0; j < 4; ++j)
                    wh[g][q][j] = Ws[g][q * DSTRIDE + FEAT + j];
    }
    float h[4] = {0.f, 0.f, 0.f, 0.f};
    float cc[4] = {0.f, 0.f, 0.f, 0.f};
    for (int s = 0; s < STEPS; ++s) {
        const int sr = s & 31;
        const int cb = c + ((s - WARM) >> 5);   // floor(n/32); n = c*32 + s - WARM
        const int cbc = cb < 0 ? 0 : cb;
        const float* p = px2 + ((size_t)sr * 256 + cbc) * 16;
        float4 PP[4];
        PP[0] = *(const float4*)(p + 0);
        PP[1] = *(const float4*)(p + 4);
        PP[2] = *(const float4*)(p + 8);
        PP[3] = *(const float4*)(p + 12);
        float act[4][4];
#pragma unroll
        for (int g = 0; g < 4; ++g) {
            float z0 = PP[g].x, z1 = PP[g].y, z2 = PP[g].z, z3 = PP[g].w;
#pragma unroll
            for (int j = 0; j < 4; ++j) {
                z0 = fmaf(h[j], wh[g][0][j], z0);
                z1 = fmaf(h[j], wh[g][1][j], z1);
                z2 = fmaf(h[j], wh[g][2][j], z2);
                z3 = fmaf(h[j], wh[g][3][j], z3);
            }
            const float c0 = cosf(z0), c1 = cosf(z1);
            const float c2 = cosf(z2), c3 = cosf(z3);
            const float m01 = c0 * c1, t23 = c2 * c3;
            const float y0 = c1 * t23, y1 = m01, y2 = m01 * c2, y3 = m01 * t23;
            if (g == 2) {
                act[g][0] = tanhf(y0); act[g][1] = tanhf(y1);
                act[g][2] = tanhf(y2); act[g][3] = tanhf(y3);
            } else {
                act[g][0] = sigm(y0); act[g][1] = sigm(y1);
                act[g][2] = sigm(y2); act[g][3] = sigm(y3);
            }
        }
        if (cb >= 0) {
#pragma unroll
            for (int q = 0; q < 4; ++q) {
                const float cn = fmaf(act[0][q], cc[q], act[1][q] * act[2][q]);
                cc[q] = cn;
                h[q] = act[3][q] * tanhf(cn);
            }
        }
        if (s >= WARM) {
            const int n = (c << 5) + (s - WARM);
            *(float4*)(hout + (size_t)n * 4) = make_float4(h[0], h[1], h[2], h[3]);
        }
    }
}

// ---------------------------------------------------------------------------
// K3a: rows 0..8175. out[n,k] = sum_q h[n,q]*Wfin[k,q] + bfin[k]; F32 OUT.
// Never writes the hout region (rows 8176..8191).
// ---------------------------------------------------------------------------
__global__ __launch_bounds__(256) void k_out_main(
    const float* __restrict__ hout,
    const float* __restrict__ Wfin, const float* __restrict__ bfin,
    float* __restrict__ out)
{
    const int n = blockIdx.x;
    const int ko = threadIdx.x * 8;
    const float4 h = *(const float4*)(hout + (size_t)n * 4);
    const float4 b0 = *(const float4*)(bfin + ko);
    const float4 b1 = *(const float4*)(bfin + ko + 4);
    const float bb[8] = {b0.x, b0.y, b0.z, b0.w, b1.x, b1.y, b1.z, b1.w};
    float o[8];
#pragma unroll
    for (int j = 0; j < 8; ++j) {
        const float4 w = *(const float4*)(Wfin + (size_t)(ko + j) * 4);
        float v = bb[j];
        v = fmaf(h.x, w.x, v); v = fmaf(h.y, w.y, v);
        v = fmaf(h.z, w.z, v); v = fmaf(h.w, w.w, v);
        o[j] = v;
    }
    float* dst = out + (size_t)n * 2048 + ko;
    *(float4*)(dst)     = make_float4(o[0], o[1], o[2], o[3]);
    *(float4*)(dst + 4) = make_float4(o[4], o[5], o[6], o[7]);
}

// ---------------------------------------------------------------------------
// K3b: rows 8176..8191 — these rows' bytes hold hout. One block: stage the
// 16 h-vectors (64 floats) to LDS, barrier, then overwrite. Race-free.
// 256 threads: 16 threads per row, 128 cols each.
// ---------------------------------------------------------------------------
__global__ __launch_bounds__(256) void k_out_tail(
    const float* __restrict__ hout,
    const float* __restrict__ Wfin, const float* __restrict__ bfin,
    float* __restrict__ out)
{
    __shared__ float hs[16 * 4];
    const int t = threadIdx.x;
    if (t < 64) hs[t] = hout[(size_t)8176 * 4 + t];
    __syncthreads();
    const int r = t >> 4;              // 0..15 local row
    const int n = 8176 + r;
    const int c0 = (t & 15) * 128;     // col block of 128
    const float4 h = *(const float4*)(&hs[r * 4]);
    for (int j = 0; j < 128; j += 8) {
        const int ko = c0 + j;
        const float4 b0 = *(const float4*)(bfin + ko);
        const float4 b1 = *(const float4*)(bfin + ko + 4);
        const float bb[8] = {b0.x, b0.y, b0.z, b0.w, b1.x, b1.y, b1.z, b1.w};
        float o[8];
#pragma unroll
        for (int jj = 0; jj < 8; ++jj) {
            const float4 w = *(const float4*)(Wfin + (size_t)(ko + jj) * 4);
            float v = bb[jj];
            v = fmaf(h.x, w.x, v); v = fmaf(h.y, w.y, v);
            v = fmaf(h.z, w.z, v); v = fmaf(h.w, w.w, v);
            o[jj] = v;
        }
        float* dst = out + (size_t)n * 2048 + ko;
        *(float4*)(dst)     = make_float4(o[0], o[1], o[2], o[3]);
        *(float4*)(dst + 4) = make_float4(o[4], o[5], o[6], o[7]);
    }
}

// Sentinel: fills out with 123.0f — fires only on input-layout mismatch.
__global__ __launch_bounds__(256) void k_sentinel(float* __restrict__ out) {
    const size_t i = (size_t)blockIdx.x * 256 + threadIdx.x;
    *(float4*)(out + i * 4) = make_float4(123.f, 123.f, 123.f, 123.f);
}

extern "C" void kernel_launch(void* const* d_in, const int* in_sizes, int n_in,
                              void* d_out, int out_size, void* d_ws, size_t ws_size,
                              hipStream_t stream)
{
    const float* feat = (const float*)d_in[0];
    const float* Wf   = (const float*)d_in[1];
    const float* bfp  = (const float*)d_in[2];
    const float* Wi   = (const float*)d_in[3];
    const float* bip  = (const float*)d_in[4];
    const float* Wg   = (const float*)d_in[5];
    const float* bgp  = (const float*)d_in[6];
    const float* Wo   = (const float*)d_in[7];
    const float* bop  = (const float*)d_in[8];
    const float* thf  = (const float*)d_in[9];
    const float* thi  = (const float*)d_in[10];
    const float* thg  = (const float*)d_in[11];
    const float* tho  = (const float*)d_in[12];
    const float* Wfin = (const float*)d_in[13];
    const float* bfin = (const float*)d_in[14];

    bool ok = (n_in == 15) &&
              in_sizes[0] == 8192 * 2048 &&
              in_sizes[1] == 8208 && in_sizes[3] == 8208 &&
              in_sizes[5] == 8208 && in_sizes[7] == 8208 &&
              in_sizes[2] == 4 && in_sizes[4] == 4 &&
              in_sizes[6] == 4 && in_sizes[8] == 4 &&
              in_sizes[9] == 4 && in_sizes[10] == 4 &&
              in_sizes[11] == 4 && in_sizes[12] == 4 &&
              in_sizes[13] == 8192 && in_sizes[14] == 2048 &&
              out_size == 8192 * 2048;
    if (!ok) {
        hipLaunchKernelGGL(k_sentinel, dim3(8192 * 2048 / 1024), dim3(256), 0,
                           stream, (float*)d_out);
        return;
    }

    // F32 output = 64 MB. Zero workspace: px2 = head 512 KB (rows 0..63),
    // hout = tail 128 KB (rows 8176..8191). Consumers ordered on `stream`.
    char* ob = (char*)d_out;
    float* px2  = (float*)ob;
    float* hout = (float*)(ob + (size_t)NN * 2048 * 4 - (size_t)NN * 16);
    float* out  = (float*)d_out;

    hipLaunchKernelGGL(k_px, dim3(512), dim3(256), 0, stream,
                       feat, Wf, Wi, Wg, Wo, bfp, bip, bgp, bop,
                       thf, thi, thg, tho, px2);
    hipLaunchKernelGGL(k_scan, dim3(1), dim3(256), 0, stream,
                       Wf, Wi, Wg, Wo, px2, hout);
    hipLaunchKernelGGL(k_out_main, dim3(NN - 16), dim3(256), 0, stream,
                       hout, Wfin, bfin, out);
    hipLaunchKernelGGL(k_out_tail, dim3(1), dim3(256), 0, stream,
                       hout, Wfin, bfin, out);
}

// Round 7
// 280.528 us; speedup vs baseline: 1.9392x; 1.9392x over previous
//
#include <hip/hip_runtime.h>
#include <stdint.h>
#include <math.h>

typedef unsigned int uint_t;

#define FEAT 2048
#define DSTRIDE 2052   // FEAT + HIDDEN
#define WARM 64
#define LCH 16
#define STEPS (WARM + LCH)
#define NCH (NN / LCH)
#define NN 8192

__device__ __forceinline__ float sigm_f(float x) {
    return __builtin_amdgcn_rcpf(1.f + __expf(-x));
}
__device__ __forceinline__ float tanh_f(float x) {
    // 1 - 2/(e^2x + 1); rcp is ~1 ulp, fine at 1e-2 threshold
    return 1.f - 2.f * __builtin_amdgcn_rcpf(__expf(2.f * x) + 1.f);
}

// ---------------------------------------------------------------------------
// K1 (f32 inputs): px2[n][gq] = feat[n,:]·Wx[gq,:2048] + b[gq] + th[gq]
// 512 blocks x 16 rows; W (16x2048 f32 = 128 KB) staged via LDS in four
// 32 KB chunks. px2 = 512 KB at head of d_out (f32 rows 0..63), consumed by
// k_scan before k_out_main overwrites it.
// ---------------------------------------------------------------------------
__global__ __launch_bounds__(256) void k_px(
    const float* __restrict__ feat,
    const float* __restrict__ Wf, const float* __restrict__ Wi,
    const float* __restrict__ Wg, const float* __restrict__ Wo,
    const float* __restrict__ bfp, const float* __restrict__ bip,
    const float* __restrict__ bgp, const float* __restrict__ bop,
    const float* __restrict__ thf, const float* __restrict__ thi,
    const float* __restrict__ thg, const float* __restrict__ tho,
    float* __restrict__ px2)
{
    __shared__ float Wl[16 * 512];
    const int t = threadIdx.x;
    const int wave = t >> 6, lane = t & 63;
    const int rowBase = blockIdx.x * 16;
    const float* Ws[4] = {Wf, Wi, Wg, Wo};

    float acc[4][16];
#pragma unroll
    for (int r = 0; r < 4; ++r)
#pragma unroll
        for (int i = 0; i < 16; ++i) acc[r][i] = 0.f;

    for (int ch = 0; ch < 4; ++ch) {
        __syncthreads();
        for (int i4 = t; i4 < 2048; i4 += 256) {
            const int gq = i4 >> 7;
            const int jj = (i4 & 127) << 2;
            const int g = gq >> 2, q = gq & 3;
            const float4 v = *(const float4*)(Ws[g] + q * DSTRIDE + ch * 512 + jj);
            *(float4*)(&Wl[gq * 512 + jj]) = v;
        }
        __syncthreads();
#pragma unroll
        for (int rr = 0; rr < 4; ++rr) {
            const int n = rowBase + wave * 4 + rr;
            const float* fp = feat + (size_t)n * FEAT + ch * 512 + lane * 8;
            const float4 fa = *(const float4*)(fp);
            const float4 fb = *(const float4*)(fp + 4);
#pragma unroll
            for (int gq = 0; gq < 16; ++gq) {
                const float4 wa = *(const float4*)(&Wl[gq * 512 + lane * 8]);
                const float4 wb = *(const float4*)(&Wl[gq * 512 + lane * 8 + 4]);
                float a = acc[rr][gq];
                a = fmaf(fa.x, wa.x, a); a = fmaf(fa.y, wa.y, a);
                a = fmaf(fa.z, wa.z, a); a = fmaf(fa.w, wa.w, a);
                a = fmaf(fb.x, wb.x, a); a = fmaf(fb.y, wb.y, a);
                a = fmaf(fb.z, wb.z, a); a = fmaf(fb.w, wb.w, a);
                acc[rr][gq] = a;
            }
        }
    }

    float bth[16];
    {
        const float* bs[4] = {bfp, bip, bgp, bop};
        const float* ts[4] = {thf, thi, thg, tho};
#pragma unroll
        for (int g = 0; g < 4; ++g)
#pragma unroll
            for (int q = 0; q < 4; ++q)
                bth[g * 4 + q] = bs[g][q] + ts[g][q];
    }

#pragma unroll
    for (int rr = 0; rr < 4; ++rr) {
#pragma unroll
        for (int i = 0; i < 16; ++i) {
            float v = acc[rr][i];
#pragma unroll
            for (int m = 32; m > 0; m >>= 1) v += __shfl_xor(v, m, 64);
            acc[rr][i] = v + bth[i];
        }
        if (lane == 0) {
            const int n = rowBase + wave * 4 + rr;
            float* dst = px2 + (size_t)n * 16;
            *(float4*)(dst + 0)  = make_float4(acc[rr][0],  acc[rr][1],  acc[rr][2],  acc[rr][3]);
            *(float4*)(dst + 4)  = make_float4(acc[rr][4],  acc[rr][5],  acc[rr][6],  acc[rr][7]);
            *(float4*)(dst + 8)  = make_float4(acc[rr][8],  acc[rr][9],  acc[rr][10], acc[rr][11]);
            *(float4*)(dst + 12) = make_float4(acc[rr][12], acc[rr][13], acc[rr][14], acc[rr][15]);
        }
    }
}

// ---------------------------------------------------------------------------
// K2: chunked scan, 512 chunks x 16 steps, 64-step warmup from (h,c)=(0,0)
// (chunks 0..3 exact; contraction f<=sigma(1)=0.731 -> warmup error <2e-9,
// adversarial bound 1.4e-5; chunk machinery proven bit-exact in R5).
// 2 blocks x 256 threads; chunks fully independent. Fast transcendentals:
// __cosf/__expf/v_rcp (error ~1e-6 vs 1.06e-2 threshold).
// qlayer(z,th) = [c1c2c3, c0c1, c0c1c2, c0c1c2c3], c_w = cos(z_w + th_w)
// (theta pre-added by k_px). hout = LAST 128 KB of d_out (rows 8176..8191).
// ---------------------------------------------------------------------------
__global__ __launch_bounds__(256) void k_scan(
    const float* __restrict__ Wf, const float* __restrict__ Wi,
    const float* __restrict__ Wg, const float* __restrict__ Wo,
    const float* __restrict__ px2, float* __restrict__ hout)
{
    const int c = blockIdx.x * 256 + threadIdx.x;   // chunk id 0..511
    float wh[4][4][4];           // [gate][q][j]
    {
        const float* Ws[4] = {Wf, Wi, Wg, Wo};
#pragma unroll
        for (int g = 0; g < 4; ++g)
#pragma unroll
            for (int q = 0; q < 4; ++q)
#pragma unroll
                for (int j = 0; j < 4; ++j)
                    wh[g][q][j] = Ws[g][q * DSTRIDE + FEAT + j];
    }
    float h[4] = {0.f, 0.f, 0.f, 0.f};
    float cc[4] = {0.f, 0.f, 0.f, 0.f};
    for (int s = 0; s < STEPS; ++s) {
        const int n = c * LCH + s - WARM;
        const int nc = n < 0 ? 0 : n;
        const float* p = px2 + (size_t)nc * 16;
        float4 PP[4];
        PP[0] = *(const float4*)(p + 0);
        PP[1] = *(const float4*)(p + 4);
        PP[2] = *(const float4*)(p + 8);
        PP[3] = *(const float4*)(p + 12);
        float act[4][4];
#pragma unroll
        for (int g = 0; g < 4; ++g) {
            float z0 = PP[g].x, z1 = PP[g].y, z2 = PP[g].z, z3 = PP[g].w;
#pragma unroll
            for (int j = 0; j < 4; ++j) {
                z0 = fmaf(h[j], wh[g][0][j], z0);
                z1 = fmaf(h[j], wh[g][1][j], z1);
                z2 = fmaf(h[j], wh[g][2][j], z2);
                z3 = fmaf(h[j], wh[g][3][j], z3);
            }
            const float c0 = __cosf(z0), c1 = __cosf(z1);
            const float c2 = __cosf(z2), c3 = __cosf(z3);
            const float m01 = c0 * c1, t23 = c2 * c3;
            const float y0 = c1 * t23, y1 = m01, y2 = m01 * c2, y3 = m01 * t23;
            if (g == 2) {
                act[g][0] = tanh_f(y0); act[g][1] = tanh_f(y1);
                act[g][2] = tanh_f(y2); act[g][3] = tanh_f(y3);
            } else {
                act[g][0] = sigm_f(y0); act[g][1] = sigm_f(y1);
                act[g][2] = sigm_f(y2); act[g][3] = sigm_f(y3);
            }
        }
        if (n >= 0) {
#pragma unroll
            for (int q = 0; q < 4; ++q) {
                const float cn = fmaf(act[0][q], cc[q], act[1][q] * act[2][q]);
                cc[q] = cn;
                h[q] = act[3][q] * tanh_f(cn);
            }
        }
        if (s >= WARM) {
            *(float4*)(hout + (size_t)n * 4) = make_float4(h[0], h[1], h[2], h[3]);
        }
    }
}

// ---------------------------------------------------------------------------
// K3a: rows 0..8175. out[n,k] = sum_q h[n,q]*Wfin[k,q] + bfin[k]; f32 out.
// Never writes the hout region (rows 8176..8191).
// ---------------------------------------------------------------------------
__global__ __launch_bounds__(256) void k_out_main(
    const float* __restrict__ hout,
    const float* __restrict__ Wfin, const float* __restrict__ bfin,
    float* __restrict__ out)
{
    const int n = blockIdx.x;
    const int ko = threadIdx.x * 8;
    const float4 h = *(const float4*)(hout + (size_t)n * 4);
    const float4 b0 = *(const float4*)(bfin + ko);
    const float4 b1 = *(const float4*)(bfin + ko + 4);
    const float bb[8] = {b0.x, b0.y, b0.z, b0.w, b1.x, b1.y, b1.z, b1.w};
    float o[8];
#pragma unroll
    for (int j = 0; j < 8; ++j) {
        const float4 w = *(const float4*)(Wfin + (size_t)(ko + j) * 4);
        float v = bb[j];
        v = fmaf(h.x, w.x, v); v = fmaf(h.y, w.y, v);
        v = fmaf(h.z, w.z, v); v = fmaf(h.w, w.w, v);
        o[j] = v;
    }
    float* dst = out + (size_t)n * 2048 + ko;
    *(float4*)(dst)     = make_float4(o[0], o[1], o[2], o[3]);
    *(float4*)(dst + 4) = make_float4(o[4], o[5], o[6], o[7]);
}

// ---------------------------------------------------------------------------
// K3b: rows 8176..8191 (bytes hold hout). Stage 16 h-vectors in LDS, barrier,
// overwrite. 16 threads/row x 128 cols.
// ---------------------------------------------------------------------------
__global__ __launch_bounds__(256) void k_out_tail(
    const float* __restrict__ hout,
    const float* __restrict__ Wfin, const float* __restrict__ bfin,
    float* __restrict__ out)
{
    __shared__ float hs[16 * 4];
    const int t = threadIdx.x;
    if (t < 64) hs[t] = hout[(size_t)8176 * 4 + t];
    __syncthreads();
    const int r = t >> 4;
    const int n = 8176 + r;
    const int c0 = (t & 15) * 128;
    const float4 h = *(const float4*)(&hs[r * 4]);
    for (int j = 0; j < 128; j += 8) {
        const int ko = c0 + j;
        const float4 b0 = *(const float4*)(bfin + ko);
        const float4 b1 = *(const float4*)(bfin + ko + 4);
        const float bb[8] = {b0.x, b0.y, b0.z, b0.w, b1.x, b1.y, b1.z, b1.w};
        float o[8];
#pragma unroll
        for (int jj = 0; jj < 8; ++jj) {
            const float4 w = *(const float4*)(Wfin + (size_t)(ko + jj) * 4);
            float v = bb[jj];
            v = fmaf(h.x, w.x, v); v = fmaf(h.y, w.y, v);
            v = fmaf(h.z, w.z, v); v = fmaf(h.w, w.w, v);
            o[jj] = v;
        }
        float* dst = out + (size_t)n * 2048 + ko;
        *(float4*)(dst)     = make_float4(o[0], o[1], o[2], o[3]);
        *(float4*)(dst + 4) = make_float4(o[4], o[5], o[6], o[7]);
    }
}

__global__ __launch_bounds__(256) void k_sentinel(float* __restrict__ out) {
    const size_t i = (size_t)blockIdx.x * 256 + threadIdx.x;
    *(float4*)(out + i * 4) = make_float4(123.f, 123.f, 123.f, 123.f);
}

extern "C" void kernel_launch(void* const* d_in, const int* in_sizes, int n_in,
                              void* d_out, int out_size, void* d_ws, size_t ws_size,
                              hipStream_t stream)
{
    const float* feat = (const float*)d_in[0];
    const float* Wf   = (const float*)d_in[1];
    const float* bfp  = (const float*)d_in[2];
    const float* Wi   = (const float*)d_in[3];
    const float* bip  = (const float*)d_in[4];
    const float* Wg   = (const float*)d_in[5];
    const float* bgp  = (const float*)d_in[6];
    const float* Wo   = (const float*)d_in[7];
    const float* bop  = (const float*)d_in[8];
    const float* thf  = (const float*)d_in[9];
    const float* thi  = (const float*)d_in[10];
    const float* thg  = (const float*)d_in[11];
    const float* tho  = (const float*)d_in[12];
    const float* Wfin = (const float*)d_in[13];
    const float* bfin = (const float*)d_in[14];

    bool ok = (n_in == 15) &&
              in_sizes[0] == 8192 * 2048 &&
              in_sizes[1] == 8208 && in_sizes[3] == 8208 &&
              in_sizes[5] == 8208 && in_sizes[7] == 8208 &&
              in_sizes[2] == 4 && in_sizes[4] == 4 &&
              in_sizes[6] == 4 && in_sizes[8] == 4 &&
              in_sizes[9] == 4 && in_sizes[10] == 4 &&
              in_sizes[11] == 4 && in_sizes[12] == 4 &&
              in_sizes[13] == 8192 && in_sizes[14] == 2048 &&
              out_size == 8192 * 2048;
    if (!ok) {
        hipLaunchKernelGGL(k_sentinel, dim3(8192 * 2048 / 1024), dim3(256), 0,
                           stream, (float*)d_out);
        return;
    }

    // F32 output = 64 MB. Zero workspace: px2 = head 512 KB (rows 0..63),
    // hout = tail 128 KB (rows 8176..8191). Consumers ordered on `stream`.
    char* ob = (char*)d_out;
    float* px2  = (float*)ob;
    float* hout = (float*)(ob + (size_t)NN * 2048 * 4 - (size_t)NN * 16);
    float* out  = (float*)d_out;

    hipLaunchKernelGGL(k_px, dim3(512), dim3(256), 0, stream,
                       feat, Wf, Wi, Wg, Wo, bfp, bip, bgp, bop,
                       thf, thi, thg, tho, px2);
    hipLaunchKernelGGL(k_scan, dim3(2), dim3(256), 0, stream,
                       Wf, Wi, Wg, Wo, px2, hout);
    hipLaunchKernelGGL(k_out_main, dim3(NN - 16), dim3(256), 0, stream,
                       hout, Wfin, bfin, out);
    hipLaunchKernelGGL(k_out_tail, dim3(1), dim3(256), 0, stream,
                       hout, Wfin, bfin, out);
}